// Round 3
// baseline (534.549 us; speedup 1.0000x reference)
//
#include <hip/hip_runtime.h>
#include <stdint.h>

// Problem constants
#define N_ATOM 2048
#define K_TOT  32768        // N_ATOM * 16  (k = b*16 + f)
#define KCH    2048         // k per block (16 K-chunks)
#define BK2    128          // k per pipeline iteration
#define NIT    (KCH / BK2)  // 16

typedef __attribute__((ext_vector_type(8))) short bf16x8;
typedef __attribute__((ext_vector_type(4))) float f32x4;

// f32 -> bf16 round-to-nearest-even (used in gt/bond staging)
__device__ __forceinline__ unsigned short f2bf(float x) {
  union { float f; uint32_t u; } v; v.f = x;
  uint32_t r = v.u + 0x7FFFu + ((v.u >> 16) & 1u);
  return (unsigned short)(r >> 16);
}

// pack two f32 -> bf16x2 (round-to-nearest, ties-down): 2 v_add + 1 v_perm
__device__ __forceinline__ uint32_t pack_bf2(float x, float y) {
  union { float f; uint32_t u; } a, b;
  a.f = x; b.f = y;
  uint32_t au = a.u + 0x7FFFu;
  uint32_t bu = b.u + 0x7FFFu;
  return __builtin_amdgcn_perm(bu, au, 0x07060302u);
}

// ---------------------------------------------------------------------------
// Kernel 1 (merged): blocks 0..255  = G[b][o][f] = sum_d node[b,d]*filters[o,f,d]
//                    blocks 256..383 = bond-term epilogue init of out[a][o]
// ---------------------------------------------------------------------------
__global__ __launch_bounds__(256) void k_pre(const float* __restrict__ node,
                                             const float* __restrict__ filt,
                                             const float* __restrict__ bond,
                                             unsigned short* __restrict__ Gt,
                                             float* __restrict__ out) {
  __shared__ unsigned short SM[2 * 128 * 136];  // 69,632 B, overlaid
  const int t   = threadIdx.x;
  const int bid = blockIdx.x;

  if (bid < 256) {
    // ---- GEMM: C[m=b][n=o*16+f] = node(2048x128) @ filters_rows(n,:128)^T ----
    unsigned short* As = SM;              // [m][k] bf16, stride 136
    unsigned short* Bs = SM + 128 * 136;  // [n][k] bf16, stride 136
    const int b0 = (bid & 15) * 128;
    const int n0 = (bid >> 4) * 128;

#pragma unroll
    for (int rep = 0; rep < 16; ++rep) {
      int q = rep * 256 + t;
      int row = q >> 5, c4 = q & 31;
      float4 v = *(const float4*)(node + (size_t)(b0 + row) * 128 + c4 * 4);
      unsigned short* dst = &As[row * 136 + c4 * 4];
      dst[0] = f2bf(v.x); dst[1] = f2bf(v.y); dst[2] = f2bf(v.z); dst[3] = f2bf(v.w);
    }
#pragma unroll
    for (int rep = 0; rep < 32; ++rep) {
      int q = rep * 256 + t;
      int row = q >> 6, c2 = q & 63;
      float2 v = *(const float2*)(filt + (size_t)(n0 + row) * 130 + c2 * 2);
      unsigned short* dst = &Bs[row * 136 + c2 * 2];
      dst[0] = f2bf(v.x); dst[1] = f2bf(v.y);
    }
    __syncthreads();

    const int w = t >> 6, l = t & 63;
    const int lm = l & 15, q4 = l >> 4;

    f32x4 acc[2][8];
#pragma unroll
    for (int ms = 0; ms < 2; ++ms)
#pragma unroll
      for (int ns = 0; ns < 8; ++ns)
        acc[ms][ns] = (f32x4){0.f, 0.f, 0.f, 0.f};

#pragma unroll
    for (int ks = 0; ks < 4; ++ks) {
      int ko = ks * 32 + q4 * 8;
      bf16x8 a[2], b[8];
#pragma unroll
      for (int ms = 0; ms < 2; ++ms) {
        int m = w * 32 + ms * 16 + lm;
        a[ms] = *(const bf16x8*)&As[m * 136 + ko];
      }
#pragma unroll
      for (int ns = 0; ns < 8; ++ns) {
        int n = ns * 16 + lm;
        b[ns] = *(const bf16x8*)&Bs[n * 136 + ko];
      }
#pragma unroll
      for (int ms = 0; ms < 2; ++ms)
#pragma unroll
        for (int ns = 0; ns < 8; ++ns)
          acc[ms][ns] = __builtin_amdgcn_mfma_f32_16x16x32_bf16(a[ms], b[ns], acc[ms][ns], 0, 0, 0);
    }

#pragma unroll
    for (int ms = 0; ms < 2; ++ms)
#pragma unroll
      for (int ns = 0; ns < 8; ++ns)
#pragma unroll
        for (int i = 0; i < 4; ++i) {
          int m = w * 32 + ms * 16 + q4 * 4 + i;
          int n = ns * 16 + lm;
          Gt[(size_t)(b0 + m) * 2048 + n0 + n] = f2bf(acc[ms][ns][i]);
        }
  } else {
    // ---- bond term: out[a][o] = sum_{f,j} bond[a,f,j] * filters[o,f,128+j] ----
    float* fb = (float*)SM;               // [o][f*2+j], 16 KB
    float* bl = (float*)SM + 128 * 32;    // [a_rel][f*2+j], 2 KB
    const int a0 = (bid - 256) * 16;

#pragma unroll
    for (int r = 0; r < 16; ++r) {
      int idx = r * 256 + t;              // 4096 = 128 o * 32
      int o = idx >> 5, fj = idx & 31;
      int f = fj >> 1, j = fj & 1;
      fb[idx] = filt[(size_t)o * 2080 + f * 130 + 128 + j];
    }
    bl[t]       = bond[(size_t)a0 * 32 + t];
    bl[256 + t] = bond[(size_t)a0 * 32 + 256 + t];
    __syncthreads();

#pragma unroll
    for (int r = 0; r < 8; ++r) {
      int idx = r * 256 + t;              // 2048 = 16 a * 128 o
      int aa = idx >> 7, o = idx & 127;
      const float2* bp = (const float2*)&bl[aa * 32];
      const float2* fp = (const float2*)&fb[o * 32];
      float acc = 0.f;
#pragma unroll
      for (int f = 0; f < 16; ++f) {
        float2 b2 = bp[f], f2 = fp[f];
        acc += b2.x * f2.x + b2.y * f2.y;
      }
      out[(size_t)(a0 + aa) * 128 + o] = acc;
    }
  }
}

// ---------------------------------------------------------------------------
// Kernel 2: out[a][o] += conn2d(2048 x 32768) @ G(32768 x 128), split-K=16.
//
// BARRIER-FREE version. Rationale: B (Gt, 8 MB) is L2/LLC-resident and each
// wave reads the full 32 KB B-tile exactly once per iteration anyway
// (4 kk x 8 ns x 64 lanes x 16 B, zero intra-wave duplication). The LDS
// round-trip only saved cross-wave L2 re-reads (~1 GB aggregate over the
// kernel, well inside L2's 35 TB/s) while forcing a 4-wave s_barrier every
// iteration — the last collective stall in the kernel. Now:
//   - B: bf16x8 fragments load straight from L2 at the MFMA consumption
//     point; per instruction the wave covers two contiguous 512 B segments.
//   - A: unchanged — nontemporal (stream-once, preserve L2 for Gt),
//     register double-buffered, prefetched 2 iterations ahead.
//   - NO LDS, NO s_barrier, NO manual waitcnt: every wave fully independent,
//     so the CU's HBM demand never collectively stalls.
// Numerics identical (same fragment values, same accumulation order).
// ---------------------------------------------------------------------------
__global__ __launch_bounds__(256, 2) void k_main(const float* __restrict__ conn,
                                                 const unsigned short* __restrict__ Gt,
                                                 float* __restrict__ out) {
  const int t  = threadIdx.x;
  const int w  = t >> 6, l = t & 63;      // w in 0..3
  const int lm = l & 15, q4 = l >> 4;
  const int a0 = blockIdx.x * 64;         // 64 rows per block
  const int kc = blockIdx.y * KCH;

  f32x4 acc[8];
#pragma unroll
  for (int ns = 0; ns < 8; ++ns)
    acc[ns] = (f32x4){0.f, 0.f, 0.f, 0.f};

  // this wave's 16 C-rows are w*16 .. w*16+15; lane lm owns row w*16+lm
  const float* arow = conn + (size_t)(a0 + w * 16 + lm) * K_TOT;

  // per-lane B base: short index = (b_base + b_rel)*2048 + (ns*16+lm)*16 + f0
  // with b_rel = 2*kk + (q4>>1), f0 = (q4&1)*8. Fold lane-constant parts:
  const unsigned short* gB0 =
      Gt + (size_t)(kc >> 4) * 2048 + (size_t)(q4 >> 1) * 2048 + lm * 16 + (q4 & 1) * 8;

  // ---- A register loads, double-buffered: [buf][kk][lo/hi] fp32, nt ----
  f32x4 Ar[2][4][2];
#define LOADA(BUF, K0)                                                      \
  do {                                                                      \
    _Pragma("unroll") for (int kk = 0; kk < 4; ++kk) {                      \
      const float* p = arow + (K0) + kk * 32 + q4 * 8;                      \
      Ar[BUF][kk][0] = __builtin_nontemporal_load((const f32x4*)p);         \
      Ar[BUF][kk][1] = __builtin_nontemporal_load((const f32x4*)(p + 4));   \
    }                                                                       \
  } while (0)

  // prologue: A for iterations 0 and 1 in flight
  LOADA(0, kc);
  LOADA(1, kc + BK2);

#pragma unroll
  for (int it = 0; it < NIT; ++it) {
    const int cur = it & 1;  // compile-time after full unroll

    // convert A_it (compiler inserts the counted vmcnt on Ar[cur] uses)
    bf16x8 af[4];
#pragma unroll
    for (int kk = 0; kk < 4; ++kk) {
      f32x4 lo = Ar[cur][kk][0], hi = Ar[cur][kk][1];
      union { bf16x8 v; uint32_t u[4]; } cvt;
      cvt.u[0] = pack_bf2(lo[0], lo[1]);
      cvt.u[1] = pack_bf2(lo[2], lo[3]);
      cvt.u[2] = pack_bf2(hi[0], hi[1]);
      cvt.u[3] = pack_bf2(hi[2], hi[3]);
      af[kk] = cvt.v;
    }

    // A two iterations ahead into the buffer just freed by the convert
    if (it + 2 < NIT) LOADA(cur, kc + (it + 2) * BK2);

    // compute: 4 K-steps of 16x16x32; B straight from L2 (8 b per it)
    const unsigned short* gB = gB0 + (size_t)it * (8 * 2048);
#pragma unroll
    for (int kk = 0; kk < 4; ++kk) {
#pragma unroll
      for (int ns = 0; ns < 8; ++ns) {
        bf16x8 b = *(const bf16x8*)(gB + kk * 4096 + ns * 256);
        acc[ns] = __builtin_amdgcn_mfma_f32_16x16x32_bf16(af[kk], b, acc[ns], 0, 0, 0);
      }
    }
  }
#undef LOADA

  // epilogue: split-K combine via fp32 atomics (16-lane coalesced segments)
#pragma unroll
  for (int ns = 0; ns < 8; ++ns)
#pragma unroll
    for (int i = 0; i < 4; ++i) {
      int m = w * 16 + q4 * 4 + i;
      int n = ns * 16 + lm;
      atomicAdd(&out[(size_t)(a0 + m) * 128 + n], acc[ns][i]);
    }
}

// ---------------------------------------------------------------------------
extern "C" void kernel_launch(void* const* d_in, const int* in_sizes, int n_in,
                              void* d_out, int out_size, void* d_ws, size_t ws_size,
                              hipStream_t stream) {
  const float* node = (const float*)d_in[0];  // (2048, 128)
  const float* conn = (const float*)d_in[1];  // (2048, 2048, 16)
  const float* bond = (const float*)d_in[2];  // (2048, 16, 2)
  const float* filt = (const float*)d_in[3];  // (128, 16, 130)
  float* out = (float*)d_out;                 // (2048, 128)

  if (ws_size < (size_t)N_ATOM * 2048 * sizeof(unsigned short)) return;  // need 8 MB
  unsigned short* Gt = (unsigned short*)d_ws;  // [b][o][f] bf16, 8 MB

  k_pre <<<dim3(384),    256, 0, stream>>>(node, filt, bond, Gt, out);
  k_main<<<dim3(32, 16), 256, 0, stream>>>(conn, Gt, out);
}

// Round 4
// 414.012 us; speedup vs baseline: 1.2911x; 1.2911x over previous
//
#include <hip/hip_runtime.h>
#include <stdint.h>

// Problem constants
#define N_ATOM 2048
#define K_TOT  32768        // N_ATOM * 16  (k = b*16 + f)
#define KCH    1024         // k per block (32 K-chunks)
#define BK2    64           // k per pipeline iteration
#define NIT    (KCH / BK2)  // 16

typedef __attribute__((ext_vector_type(8))) short bf16x8;
typedef __attribute__((ext_vector_type(4))) float f32x4;

typedef __attribute__((address_space(3))) uint32_t lds_u32;
typedef __attribute__((address_space(1))) uint32_t gbl_u32;

__device__ __forceinline__ void async_ld16(const void* g, void* l) {
  __builtin_amdgcn_global_load_lds((const gbl_u32*)g, (lds_u32*)l, 16, 0, 0);
}

// f32 -> bf16 round-to-nearest-even (used in gt/bond staging)
__device__ __forceinline__ unsigned short f2bf(float x) {
  union { float f; uint32_t u; } v; v.f = x;
  uint32_t r = v.u + 0x7FFFu + ((v.u >> 16) & 1u);
  return (unsigned short)(r >> 16);
}

// pack two f32 -> bf16x2 (round-to-nearest, ties-down): 2 v_add + 1 v_perm
__device__ __forceinline__ uint32_t pack_bf2(float x, float y) {
  union { float f; uint32_t u; } a, b;
  a.f = x; b.f = y;
  uint32_t au = a.u + 0x7FFFu;
  uint32_t bu = b.u + 0x7FFFu;
  return __builtin_amdgcn_perm(bu, au, 0x07060302u);
}

// ---------------------------------------------------------------------------
// Kernel 1 (merged): blocks 0..255  = G[b][o][f] = sum_d node[b,d]*filters[o,f,d]
//                    blocks 256..383 = bond-term epilogue init of out[a][o]
// ---------------------------------------------------------------------------
__global__ __launch_bounds__(256) void k_pre(const float* __restrict__ node,
                                             const float* __restrict__ filt,
                                             const float* __restrict__ bond,
                                             unsigned short* __restrict__ Gt,
                                             float* __restrict__ out) {
  __shared__ unsigned short SM[2 * 128 * 136];  // 69,632 B, overlaid
  const int t   = threadIdx.x;
  const int bid = blockIdx.x;

  if (bid < 256) {
    // ---- GEMM: C[m=b][n=o*16+f] = node(2048x128) @ filters_rows(n,:128)^T ----
    unsigned short* As = SM;              // [m][k] bf16, stride 136
    unsigned short* Bs = SM + 128 * 136;  // [n][k] bf16, stride 136
    const int b0 = (bid & 15) * 128;
    const int n0 = (bid >> 4) * 128;

#pragma unroll
    for (int rep = 0; rep < 16; ++rep) {
      int q = rep * 256 + t;
      int row = q >> 5, c4 = q & 31;
      float4 v = *(const float4*)(node + (size_t)(b0 + row) * 128 + c4 * 4);
      unsigned short* dst = &As[row * 136 + c4 * 4];
      dst[0] = f2bf(v.x); dst[1] = f2bf(v.y); dst[2] = f2bf(v.z); dst[3] = f2bf(v.w);
    }
#pragma unroll
    for (int rep = 0; rep < 32; ++rep) {
      int q = rep * 256 + t;
      int row = q >> 6, c2 = q & 63;
      float2 v = *(const float2*)(filt + (size_t)(n0 + row) * 130 + c2 * 2);
      unsigned short* dst = &Bs[row * 136 + c2 * 2];
      dst[0] = f2bf(v.x); dst[1] = f2bf(v.y);
    }
    __syncthreads();

    const int w = t >> 6, l = t & 63;
    const int lm = l & 15, q4 = l >> 4;

    f32x4 acc[2][8];
#pragma unroll
    for (int ms = 0; ms < 2; ++ms)
#pragma unroll
      for (int ns = 0; ns < 8; ++ns)
        acc[ms][ns] = (f32x4){0.f, 0.f, 0.f, 0.f};

#pragma unroll
    for (int ks = 0; ks < 4; ++ks) {
      int ko = ks * 32 + q4 * 8;
      bf16x8 a[2], b[8];
#pragma unroll
      for (int ms = 0; ms < 2; ++ms) {
        int m = w * 32 + ms * 16 + lm;
        a[ms] = *(const bf16x8*)&As[m * 136 + ko];
      }
#pragma unroll
      for (int ns = 0; ns < 8; ++ns) {
        int n = ns * 16 + lm;
        b[ns] = *(const bf16x8*)&Bs[n * 136 + ko];
      }
#pragma unroll
      for (int ms = 0; ms < 2; ++ms)
#pragma unroll
        for (int ns = 0; ns < 8; ++ns)
          acc[ms][ns] = __builtin_amdgcn_mfma_f32_16x16x32_bf16(a[ms], b[ns], acc[ms][ns], 0, 0, 0);
    }

#pragma unroll
    for (int ms = 0; ms < 2; ++ms)
#pragma unroll
      for (int ns = 0; ns < 8; ++ns)
#pragma unroll
        for (int i = 0; i < 4; ++i) {
          int m = w * 32 + ms * 16 + q4 * 4 + i;
          int n = ns * 16 + lm;
          Gt[(size_t)(b0 + m) * 2048 + n0 + n] = f2bf(acc[ms][ns][i]);
        }
  } else {
    // ---- bond term: out[a][o] = sum_{f,j} bond[a,f,j] * filters[o,f,128+j] ----
    float* fb = (float*)SM;               // [o][f*2+j], 16 KB
    float* bl = (float*)SM + 128 * 32;    // [a_rel][f*2+j], 2 KB
    const int a0 = (bid - 256) * 16;

#pragma unroll
    for (int r = 0; r < 16; ++r) {
      int idx = r * 256 + t;              // 4096 = 128 o * 32
      int o = idx >> 5, fj = idx & 31;
      int f = fj >> 1, j = fj & 1;
      fb[idx] = filt[(size_t)o * 2080 + f * 130 + 128 + j];
    }
    bl[t]       = bond[(size_t)a0 * 32 + t];
    bl[256 + t] = bond[(size_t)a0 * 32 + 256 + t];
    __syncthreads();

#pragma unroll
    for (int r = 0; r < 8; ++r) {
      int idx = r * 256 + t;              // 2048 = 16 a * 128 o
      int aa = idx >> 7, o = idx & 127;
      const float2* bp = (const float2*)&bl[aa * 32];
      const float2* fp = (const float2*)&fb[o * 32];
      float acc = 0.f;
#pragma unroll
      for (int f = 0; f < 16; ++f) {
        float2 b2 = bp[f], f2 = fp[f];
        acc += b2.x * f2.x + b2.y * f2.y;
      }
      out[(size_t)(a0 + aa) * 128 + o] = acc;
    }
  }
}

// ---------------------------------------------------------------------------
// Kernel 2: out[a][o] += conn2d(2048 x 32768) @ G(32768 x 128), split-K=32.
//
// R4: same verified counted-vmcnt LDS pipeline as the 407.5 µs version, but
// 4 INDEPENDENT blocks per CU (was 2). BK2 64 -> LDS 2 x 16 KB = 32 KB/block;
// __launch_bounds__(256,4) caps VGPR at 128 so 4 waves/SIMD fit. Per CU:
// 16 waves in 4 independent barrier groups — a block stalled at its barrier
// is covered by three others, keeping HBM fed through every rendezvous.
// (R3 lesson: B must stay LDS-staged; direct-L2 B exposes serial L2 latency.)
//
// Pipeline per iteration (per block):
//   - stage B_{i+1} FIRST (4 x global_load_lds, oldest in queue)
//   - convert A_i (registers, already resident)
//   - issue A_{i+2} (4 x nontemporal f32x4, newest in queue)
//   - 16 MFMA over LDS B_i
//   - s_waitcnt vmcnt(4): drains {A_{i+1}, B_{i+1}}, A_{i+2} stays in flight
//   - s_barrier (4 waves only)
// Numerics: same bf16 products and in-register accumulation; split-K
// regrouping only changes fp32 atomic add grouping.
// ---------------------------------------------------------------------------
__global__ __launch_bounds__(256, 4) void k_main(const float* __restrict__ conn,
                                                 const unsigned short* __restrict__ Gt,
                                                 float* __restrict__ out) {
  __shared__ unsigned short Bh[2][4 * 128 * 16];  // 2 x 16 KB, [b_rel][o][f]

  const int t  = threadIdx.x;
  const int w  = t >> 6, l = t & 63;      // w in 0..3
  const int lm = l & 15, q4 = l >> 4;
  const int a0 = blockIdx.x * 64;         // 64 rows per block
  const int kc = blockIdx.y * KCH;

  f32x4 acc[8];
#pragma unroll
  for (int ns = 0; ns < 8; ++ns)
    acc[ns] = (f32x4){0.f, 0.f, 0.f, 0.f};

  // this wave's 16 C-rows are w*16 .. w*16+15; lane lm owns row w*16+lm
  const float* arow = conn + (size_t)(a0 + w * 16 + lm) * K_TOT;

  // ---- B async stage: 16 KB contiguous from Gt + k0*128 shorts (4 instr) ----
  auto stageB = [&](int buf, int k0) {
    const char* gB = (const char*)(Gt + (size_t)k0 * 128);
#pragma unroll
    for (int r = 0; r < 4; ++r) {
      const void* g = gB + (size_t)(r * 256 + t) * 16;
      void* lb = (void*)((char*)&Bh[buf][0] + r * 4096 + w * 1024);  // wave-uniform
      async_ld16(g, lb);
    }
  };

  // ---- A register loads, double-buffered: [buf][kk][lo/hi] fp32, nt (4 instr) ----
  f32x4 Ar[2][2][2];
#define LOADA(BUF, K0)                                                      \
  do {                                                                      \
    _Pragma("unroll") for (int kk = 0; kk < 2; ++kk) {                      \
      const float* p = arow + (K0) + kk * 32 + q4 * 8;                      \
      Ar[BUF][kk][0] = __builtin_nontemporal_load((const f32x4*)p);         \
      Ar[BUF][kk][1] = __builtin_nontemporal_load((const f32x4*)(p + 4));   \
    }                                                                       \
  } while (0)

  // prologue: queue = [B0(4), A0(4), A1(4)]; release when B0 staged.
  stageB(0, kc);
  LOADA(0, kc);
  LOADA(1, kc + BK2);
  __builtin_amdgcn_sched_barrier(0);
  asm volatile("s_waitcnt vmcnt(8)" ::: "memory");  // oldest 4 (= B0) done
  __builtin_amdgcn_s_barrier();
  __builtin_amdgcn_sched_barrier(0);

#pragma unroll
  for (int it = 0; it < NIT; ++it) {
    const int cur = it & 1;  // compile-time after full unroll

    // issue next B tile FIRST: it must sit older than A_{it+2} in the queue
    // so the end-of-iter counted wait covers it without draining A_{it+2}.
    if (it + 1 < NIT) stageB(1 - cur, kc + (it + 1) * BK2);

    // convert A_it (resident since previous iteration's counted wait)
    bf16x8 af[2];
#pragma unroll
    for (int kk = 0; kk < 2; ++kk) {
      f32x4 lo = Ar[cur][kk][0], hi = Ar[cur][kk][1];
      union { bf16x8 v; uint32_t u[4]; } cvt;
      cvt.u[0] = pack_bf2(lo[0], lo[1]);
      cvt.u[1] = pack_bf2(lo[2], lo[3]);
      cvt.u[2] = pack_bf2(hi[0], hi[1]);
      cvt.u[3] = pack_bf2(hi[2], hi[3]);
      af[kk] = cvt.v;
    }

    // A two iterations ahead into the buffer just freed by the convert
    if (it + 2 < NIT) LOADA(cur, kc + (it + 2) * BK2);

    // compute: 2 K-steps of 16x16x32 over Bh[cur]
#pragma unroll
    for (int kk = 0; kk < 2; ++kk) {
      const int b_rel = 2 * kk + (q4 >> 1);
      const int f0 = (q4 & 1) * 8;
#pragma unroll
      for (int ns = 0; ns < 8; ++ns) {
        int o = ns * 16 + lm;
        bf16x8 b = *(const bf16x8*)&Bh[cur][b_rel * 2048 + o * 16 + f0];
        acc[ns] = __builtin_amdgcn_mfma_f32_16x16x32_bf16(af[kk], b, acc[ns], 0, 0, 0);
      }
    }

    // counted drain + raw barrier: B_{it+1} (and A_{it+1}, needed next convert
    // anyway) complete; A_{it+2}'s 4 loads stay in flight across the barrier.
    if (it + 1 < NIT) {
      __builtin_amdgcn_sched_barrier(0);
      if (it + 2 < NIT) {
        asm volatile("s_waitcnt vmcnt(4)" ::: "memory");
      } else {
        asm volatile("s_waitcnt vmcnt(0)" ::: "memory");  // it==14: no A in flight
      }
      __builtin_amdgcn_s_barrier();
      __builtin_amdgcn_sched_barrier(0);
    }
  }
#undef LOADA

  // epilogue: split-K combine via fp32 atomics (16-lane coalesced segments)
#pragma unroll
  for (int ns = 0; ns < 8; ++ns)
#pragma unroll
    for (int i = 0; i < 4; ++i) {
      int m = w * 16 + q4 * 4 + i;
      int n = ns * 16 + lm;
      atomicAdd(&out[(size_t)(a0 + m) * 128 + n], acc[ns][i]);
    }
}

// ---------------------------------------------------------------------------
extern "C" void kernel_launch(void* const* d_in, const int* in_sizes, int n_in,
                              void* d_out, int out_size, void* d_ws, size_t ws_size,
                              hipStream_t stream) {
  const float* node = (const float*)d_in[0];  // (2048, 128)
  const float* conn = (const float*)d_in[1];  // (2048, 2048, 16)
  const float* bond = (const float*)d_in[2];  // (2048, 16, 2)
  const float* filt = (const float*)d_in[3];  // (128, 16, 130)
  float* out = (float*)d_out;                 // (2048, 128)

  if (ws_size < (size_t)N_ATOM * 2048 * sizeof(unsigned short)) return;  // need 8 MB
  unsigned short* Gt = (unsigned short*)d_ws;  // [b][o][f] bf16, 8 MB

  k_pre <<<dim3(384),    256, 0, stream>>>(node, filt, bond, Gt, out);
  k_main<<<dim3(32, 32), 256, 0, stream>>>(conn, Gt, out);
}

// Round 5
// 413.095 us; speedup vs baseline: 1.2940x; 1.0022x over previous
//
#include <hip/hip_runtime.h>
#include <stdint.h>

// Problem constants
#define N_ATOM 2048
#define K_TOT  32768        // N_ATOM * 16  (k = b*16 + f)
#define KCH    2048         // k per block (16 K-chunks)
#define BK2    128          // k per pipeline iteration
#define NIT    (KCH / BK2)  // 16

typedef __attribute__((ext_vector_type(8))) short bf16x8;
typedef __attribute__((ext_vector_type(4))) float f32x4;

typedef __attribute__((address_space(3))) uint32_t lds_u32;
typedef __attribute__((address_space(1))) uint32_t gbl_u32;

__device__ __forceinline__ void async_ld16(const void* g, void* l) {
  __builtin_amdgcn_global_load_lds((const gbl_u32*)g, (lds_u32*)l, 16, 0, 0);
}

// f32 -> bf16 round-to-nearest-even (used in gt/bond staging)
__device__ __forceinline__ unsigned short f2bf(float x) {
  union { float f; uint32_t u; } v; v.f = x;
  uint32_t r = v.u + 0x7FFFu + ((v.u >> 16) & 1u);
  return (unsigned short)(r >> 16);
}

// pack two f32 -> bf16x2 (round-to-nearest, ties-down): 2 v_add + 1 v_perm
__device__ __forceinline__ uint32_t pack_bf2(float x, float y) {
  union { float f; uint32_t u; } a, b;
  a.f = x; b.f = y;
  uint32_t au = a.u + 0x7FFFu;
  uint32_t bu = b.u + 0x7FFFu;
  return __builtin_amdgcn_perm(bu, au, 0x07060302u);
}

// ---------------------------------------------------------------------------
// Kernel 1 (merged): blocks 0..255  = G[b][o][f] = sum_d node[b,d]*filters[o,f,d]
//                    blocks 256..383 = bond-term epilogue init of out[a][o]
// ---------------------------------------------------------------------------
__global__ __launch_bounds__(256) void k_pre(const float* __restrict__ node,
                                             const float* __restrict__ filt,
                                             const float* __restrict__ bond,
                                             unsigned short* __restrict__ Gt,
                                             float* __restrict__ out) {
  __shared__ unsigned short SM[2 * 128 * 136];  // 69,632 B, overlaid
  const int t   = threadIdx.x;
  const int bid = blockIdx.x;

  if (bid < 256) {
    // ---- GEMM: C[m=b][n=o*16+f] = node(2048x128) @ filters_rows(n,:128)^T ----
    unsigned short* As = SM;              // [m][k] bf16, stride 136
    unsigned short* Bs = SM + 128 * 136;  // [n][k] bf16, stride 136
    const int b0 = (bid & 15) * 128;
    const int n0 = (bid >> 4) * 128;

#pragma unroll
    for (int rep = 0; rep < 16; ++rep) {
      int q = rep * 256 + t;
      int row = q >> 5, c4 = q & 31;
      float4 v = *(const float4*)(node + (size_t)(b0 + row) * 128 + c4 * 4);
      unsigned short* dst = &As[row * 136 + c4 * 4];
      dst[0] = f2bf(v.x); dst[1] = f2bf(v.y); dst[2] = f2bf(v.z); dst[3] = f2bf(v.w);
    }
#pragma unroll
    for (int rep = 0; rep < 32; ++rep) {
      int q = rep * 256 + t;
      int row = q >> 6, c2 = q & 63;
      float2 v = *(const float2*)(filt + (size_t)(n0 + row) * 130 + c2 * 2);
      unsigned short* dst = &Bs[row * 136 + c2 * 2];
      dst[0] = f2bf(v.x); dst[1] = f2bf(v.y);
    }
    __syncthreads();

    const int w = t >> 6, l = t & 63;
    const int lm = l & 15, q4 = l >> 4;

    f32x4 acc[2][8];
#pragma unroll
    for (int ms = 0; ms < 2; ++ms)
#pragma unroll
      for (int ns = 0; ns < 8; ++ns)
        acc[ms][ns] = (f32x4){0.f, 0.f, 0.f, 0.f};

#pragma unroll
    for (int ks = 0; ks < 4; ++ks) {
      int ko = ks * 32 + q4 * 8;
      bf16x8 a[2], b[8];
#pragma unroll
      for (int ms = 0; ms < 2; ++ms) {
        int m = w * 32 + ms * 16 + lm;
        a[ms] = *(const bf16x8*)&As[m * 136 + ko];
      }
#pragma unroll
      for (int ns = 0; ns < 8; ++ns) {
        int n = ns * 16 + lm;
        b[ns] = *(const bf16x8*)&Bs[n * 136 + ko];
      }
#pragma unroll
      for (int ms = 0; ms < 2; ++ms)
#pragma unroll
        for (int ns = 0; ns < 8; ++ns)
          acc[ms][ns] = __builtin_amdgcn_mfma_f32_16x16x32_bf16(a[ms], b[ns], acc[ms][ns], 0, 0, 0);
    }

#pragma unroll
    for (int ms = 0; ms < 2; ++ms)
#pragma unroll
      for (int ns = 0; ns < 8; ++ns)
#pragma unroll
        for (int i = 0; i < 4; ++i) {
          int m = w * 32 + ms * 16 + q4 * 4 + i;
          int n = ns * 16 + lm;
          Gt[(size_t)(b0 + m) * 2048 + n0 + n] = f2bf(acc[ms][ns][i]);
        }
  } else {
    // ---- bond term: out[a][o] = sum_{f,j} bond[a,f,j] * filters[o,f,128+j] ----
    float* fb = (float*)SM;               // [o][f*2+j], 16 KB
    float* bl = (float*)SM + 128 * 32;    // [a_rel][f*2+j], 2 KB
    const int a0 = (bid - 256) * 16;

#pragma unroll
    for (int r = 0; r < 16; ++r) {
      int idx = r * 256 + t;              // 4096 = 128 o * 32
      int o = idx >> 5, fj = idx & 31;
      int f = fj >> 1, j = fj & 1;
      fb[idx] = filt[(size_t)o * 2080 + f * 130 + 128 + j];
    }
    bl[t]       = bond[(size_t)a0 * 32 + t];
    bl[256 + t] = bond[(size_t)a0 * 32 + 256 + t];
    __syncthreads();

#pragma unroll
    for (int r = 0; r < 8; ++r) {
      int idx = r * 256 + t;              // 2048 = 16 a * 128 o
      int aa = idx >> 7, o = idx & 127;
      const float2* bp = (const float2*)&bl[aa * 32];
      const float2* fp = (const float2*)&fb[o * 32];
      float acc = 0.f;
#pragma unroll
      for (int f = 0; f < 16; ++f) {
        float2 b2 = bp[f], f2 = fp[f];
        acc += b2.x * f2.x + b2.y * f2.y;
      }
      out[(size_t)(a0 + aa) * 128 + o] = acc;
    }
  }
}

// ---------------------------------------------------------------------------
// Kernel 2: out[a][o] += conn2d(2048 x 32768) @ G(32768 x 128), split-K=16.
//
// R5: PRODUCER/CONSUMER WAVE SPECIALIZATION. FIFO analysis of R2: vmcnt is a
// FIFO, and since every wave issued both B stages and A loads, the counted
// wait that drains B_{i+1} necessarily drained every A issued before it —
// capping in-flight A at one iteration (64 KB/CU) and stalling all waves
// together. Now, 320-thread blocks (5 waves):
//   - wave 4 = B producer: stages the 32 KB B tile via 32 global_load_lds,
//     vmcnt(0) (its queue is B-ONLY, and the stage had a full iteration to
//     land -> stall ~0), then barrier.
//   - waves 0-3 = consumers: queue is PURE A -> 3-deep register prefetch
//     with clean compiler-counted waits at the convert; ZERO vmcnt at
//     barriers; 16-24 KB/wave of A stays in flight across every rendezvous
//     (per-CU in-flight ~150-190 KB vs R2's 64 KB).
// LDS byte layout, fragments, rounding, accumulation order identical to R2.
// ---------------------------------------------------------------------------
__global__ __launch_bounds__(320, 2) void k_main(const float* __restrict__ conn,
                                                 const unsigned short* __restrict__ Gt,
                                                 float* __restrict__ out) {
  __shared__ unsigned short Bh[2][8 * 128 * 16];  // 2 x 32 KB, [b_rel][o][f]

  const int t  = threadIdx.x;
  const int w  = t >> 6, l = t & 63;      // w in 0..4
  const int lm = l & 15, q4 = l >> 4;
  const int a0 = blockIdx.x * 64;         // 64 rows per block
  const int kc = blockIdx.y * KCH;
  const bool producer = (w == 4);

  f32x4 acc[8];
#pragma unroll
  for (int ns = 0; ns < 8; ++ns)
    acc[ns] = (f32x4){0.f, 0.f, 0.f, 0.f};

  // consumer wave w owns C-rows w*16..w*16+15; lane lm owns row w*16+lm
  // (w&3 keeps the producer's unused pointer in-range)
  const float* arow = conn + (size_t)(a0 + (w & 3) * 16 + lm) * K_TOT;

  // ---- B stage (PRODUCER WAVE ONLY): 32 KB contiguous, 32 instrs ----
  auto stageB = [&](int buf, int k0) {
    const char* gB = (const char*)(Gt + (size_t)k0 * 128);
#pragma unroll
    for (int r = 0; r < 32; ++r) {
      const void* g = gB + (size_t)(r * 64 + l) * 16;
      void* lb = (void*)((char*)&Bh[buf][0] + r * 1024);  // wave-uniform + lane*16
      async_ld16(g, lb);
    }
  };

  // ---- A register loads, TRIPLE-buffered: [buf][kk][lo/hi] fp32, nt ----
  f32x4 Ar[3][4][2];
#define LOADA(BUF, K0)                                                      \
  do {                                                                      \
    _Pragma("unroll") for (int kk = 0; kk < 4; ++kk) {                      \
      const float* p = arow + (K0) + kk * 32 + q4 * 8;                      \
      Ar[BUF][kk][0] = __builtin_nontemporal_load((const f32x4*)p);         \
      Ar[BUF][kk][1] = __builtin_nontemporal_load((const f32x4*)(p + 4));   \
    }                                                                       \
  } while (0)

  // prologue: producer stages B0 and drains ITS OWN queue; consumers issue
  // A0..A2 which stay in flight across the raw barrier (no drain for them).
  if (producer) {
    stageB(0, kc);
    asm volatile("s_waitcnt vmcnt(0)" ::: "memory");
  } else {
    LOADA(0, kc);
    LOADA(1, kc + BK2);
    LOADA(2, kc + 2 * BK2);
  }
  __builtin_amdgcn_sched_barrier(0);
  __builtin_amdgcn_s_barrier();
  __builtin_amdgcn_sched_barrier(0);

#pragma unroll
  for (int it = 0; it < NIT; ++it) {
    const int cur = it & 1;    // compile-time after full unroll
    const int slot = it % 3;   // compile-time after full unroll

    if (producer) {
      // stage B_{it+1} into the buffer consumers just stopped reading;
      // vmcnt(0) drains ONLY the producer's B loads (queue is B-only).
      if (it + 1 < NIT) {
        stageB(1 - cur, kc + (it + 1) * BK2);
        asm volatile("s_waitcnt vmcnt(0)" ::: "memory");
      }
    } else {
      // convert A_it (compiler inserts counted vmcnt on Ar[slot] regs only)
      bf16x8 af[4];
#pragma unroll
      for (int kk = 0; kk < 4; ++kk) {
        f32x4 lo = Ar[slot][kk][0], hi = Ar[slot][kk][1];
        union { bf16x8 v; uint32_t u[4]; } cvt;
        cvt.u[0] = pack_bf2(lo[0], lo[1]);
        cvt.u[1] = pack_bf2(lo[2], lo[3]);
        cvt.u[2] = pack_bf2(hi[0], hi[1]);
        cvt.u[3] = pack_bf2(hi[2], hi[3]);
        af[kk] = cvt.v;
      }

      // A three iterations ahead into the slot just freed by the convert
      if (it + 3 < NIT) LOADA(slot, kc + (it + 3) * BK2);

      // compute: 4 K-steps of 16x16x32 over Bh[cur]
#pragma unroll
      for (int kk = 0; kk < 4; ++kk) {
        const int b_rel = 2 * kk + (q4 >> 1);
        const int f0 = (q4 & 1) * 8;
#pragma unroll
        for (int ns = 0; ns < 8; ++ns) {
          int o = ns * 16 + lm;
          bf16x8 b = *(const bf16x8*)&Bh[cur][b_rel * 2048 + o * 16 + f0];
          acc[ns] = __builtin_amdgcn_mfma_f32_16x16x32_bf16(af[kk], b, acc[ns], 0, 0, 0);
        }
      }
    }

    // raw barrier, NO vmcnt for consumers: their in-flight A survives.
    if (it + 1 < NIT) {
      __builtin_amdgcn_sched_barrier(0);
      __builtin_amdgcn_s_barrier();
      __builtin_amdgcn_sched_barrier(0);
    }
  }
#undef LOADA

  // epilogue: split-K combine via fp32 atomics (consumers only)
  if (!producer) {
#pragma unroll
    for (int ns = 0; ns < 8; ++ns)
#pragma unroll
      for (int i = 0; i < 4; ++i) {
        int m = w * 16 + q4 * 4 + i;
        int n = ns * 16 + lm;
        atomicAdd(&out[(size_t)(a0 + m) * 128 + n], acc[ns][i]);
      }
  }
}

// ---------------------------------------------------------------------------
extern "C" void kernel_launch(void* const* d_in, const int* in_sizes, int n_in,
                              void* d_out, int out_size, void* d_ws, size_t ws_size,
                              hipStream_t stream) {
  const float* node = (const float*)d_in[0];  // (2048, 128)
  const float* conn = (const float*)d_in[1];  // (2048, 2048, 16)
  const float* bond = (const float*)d_in[2];  // (2048, 16, 2)
  const float* filt = (const float*)d_in[3];  // (128, 16, 130)
  float* out = (float*)d_out;                 // (2048, 128)

  if (ws_size < (size_t)N_ATOM * 2048 * sizeof(unsigned short)) return;  // need 8 MB
  unsigned short* Gt = (unsigned short*)d_ws;  // [b][o][f] bf16, 8 MB

  k_pre <<<dim3(384),    256, 0, stream>>>(node, filt, bond, Gt, out);
  k_main<<<dim3(32, 16), 320, 0, stream>>>(conn, Gt, out);
}